// Round 11
// baseline (438.388 us; speedup 1.0000x reference)
//
#include <hip/hip_runtime.h>
#include <stdint.h>

#define HW 4096
#define NC 512
#define NB 4

typedef __attribute__((ext_vector_type(8))) _Float16 f16x8;
typedef __attribute__((ext_vector_type(4))) float f32x4;
typedef __attribute__((ext_vector_type(4))) unsigned short ush4;
typedef __attribute__((ext_vector_type(8))) unsigned short ush8;

typedef __attribute__((address_space(1))) const void* as1_cvp;
typedef __attribute__((address_space(3))) void* as3_vp;

__device__ __forceinline__ unsigned short f2h(float f) {
  union { _Float16 h; unsigned short u; } c;
  c.h = (_Float16)f;           // hardware v_cvt_f16_f32, RNE
  return c.u;
}
__device__ __forceinline__ float h2f(unsigned short u) {
  union { unsigned short u; _Float16 h; } c;
  c.u = u;
  return (float)c.h;
}

// ---------------- moments: per-(b,c) mean/rstd over 4096 spatial elems ----------
__global__ __launch_bounds__(256) void moments_k(const float* __restrict__ x,
                                                 const float* __restrict__ y,
                                                 float* __restrict__ stats) {
  int bid = blockIdx.x;          // 0..4095 : [tensor(2)][b*C+c (2048)]
  int tens = bid >> 11;
  int row = bid & 2047;
  const float* src = (tens ? y : x) + (size_t)row * HW;
  float s = 0.f, s2 = 0.f;
  for (int j = threadIdx.x; j < HW / 4; j += 256) {
    float4 v = ((const float4*)src)[j];
    s += (v.x + v.y) + (v.z + v.w);
    s2 += (v.x * v.x + v.y * v.y) + (v.z * v.z + v.w * v.w);
  }
  #pragma unroll
  for (int o = 32; o; o >>= 1) { s += __shfl_down(s, o); s2 += __shfl_down(s2, o); }
  __shared__ float rs[8];
  int w = threadIdx.x >> 6;
  if ((threadIdx.x & 63) == 0) { rs[w] = s; rs[4 + w] = s2; }
  __syncthreads();
  if (threadIdx.x == 0) {
    float S = (rs[0] + rs[1]) + (rs[2] + rs[3]);
    float S2 = (rs[4] + rs[5]) + (rs[6] + rs[7]);
    float mean = S * (1.f / HW);
    float var = S2 * (1.f / HW) - mean * mean;
    stats[tens * 4096 + row] = mean;
    stats[tens * 4096 + 2048 + row] = rsqrtf(var + 1e-5f);
  }
}

// ---- transpose f32 [c][i] -> f16 [i][c]; mode0: xnT; mode1: ynT + yH cast ------
__global__ __launch_bounds__(256) void transnorm_k(const float* __restrict__ x,
                                                   const float* __restrict__ y,
                                                   const float* __restrict__ stats,
                                                   unsigned short* __restrict__ xnT,
                                                   unsigned short* __restrict__ ynT,
                                                   unsigned short* __restrict__ yH) {
  __shared__ float tile[64][65];
  __shared__ float ms[64], rsd[64];
  int zi = blockIdx.z;            // [0,8): b = zi>>1, mode = zi&1
  int b = zi >> 1, mode = zi & 1;
  int i0 = blockIdx.x * 64, c0 = blockIdx.y * 64;
  const float* src = mode ? y : x;
  int t = threadIdx.x;
  int c = t >> 2;                 // 0..63
  int isub = (t & 3) << 4;        // 16 i's per thread
  if (t < 64) {
    int srow = (mode ? 4096 : 0) + b * NC + c0 + t;
    ms[t] = stats[srow];
    rsd[t] = stats[srow + 2048];
  }
  const float4* sp = (const float4*)(src + ((size_t)(b * NC + c0 + c)) * HW + i0 + isub);
  #pragma unroll
  for (int k = 0; k < 4; ++k) {
    float4 v = sp[k];
    int ib = isub + k * 4;
    tile[ib + 0][c] = v.x;
    tile[ib + 1][c] = v.y;
    tile[ib + 2][c] = v.z;
    tile[ib + 3][c] = v.w;
    if (mode) {   // straight f16 cast of raw y, [c][i] layout (PV B-operand)
      ush4 yo;
      yo[0] = f2h(v.x); yo[1] = f2h(v.y); yo[2] = f2h(v.z); yo[3] = f2h(v.w);
      *(ush4*)(yH + ((size_t)(b * NC + c0 + c)) * HW + i0 + isub + k * 4) = yo;
    }
  }
  __syncthreads();
  int i = t >> 2;
  int cc = (t & 3) << 4;
  size_t obase = ((size_t)b * HW + i0 + i) * NC + c0 + cc;
  unsigned short* dst = mode ? ynT : xnT;
  #pragma unroll
  for (int h = 0; h < 2; ++h) {
    ush8 o;
    #pragma unroll
    for (int e = 0; e < 8; ++e) {
      int ce = cc + h * 8 + e;
      o[e] = f2h((tile[i][ce] - ms[ce]) * rsd[ce]);
    }
    *(ush8*)(dst + obase + h * 8) = o;
  }
}

// ---- weights -> f16: z=0,1,2 transpose fw,gw,hw ; z=3 straight out_w -----------
__global__ __launch_bounds__(256) void castw_k(const float* __restrict__ fw,
                                               const float* __restrict__ gw,
                                               const float* __restrict__ hw_,
                                               const float* __restrict__ ow,
                                               unsigned short* __restrict__ fwT,
                                               unsigned short* __restrict__ gwT,
                                               unsigned short* __restrict__ hwT,
                                               unsigned short* __restrict__ owB) {
  __shared__ float tile[64][65];
  int which = blockIdx.z;
  const float* src = which == 0 ? fw : which == 1 ? gw : which == 2 ? hw_ : ow;
  unsigned short* dst = which == 0 ? fwT : which == 1 ? gwT : which == 2 ? hwT : owB;
  int r0 = blockIdx.x * 64, c0 = blockIdx.y * 64;
  int t = threadIdx.x;
  int r = t >> 2;
  int csub = (t & 3) << 4;
  const float4* sp = (const float4*)(src + (size_t)(r0 + r) * 512 + c0 + csub);
  if (which == 3) {   // straight cast
    #pragma unroll
    for (int k = 0; k < 4; ++k) {
      float4 v = sp[k];
      ush4 o;
      o[0] = f2h(v.x); o[1] = f2h(v.y); o[2] = f2h(v.z); o[3] = f2h(v.w);
      *(ush4*)(dst + (size_t)(r0 + r) * 512 + c0 + csub + k * 4) = o;
    }
    return;
  }
  #pragma unroll
  for (int k = 0; k < 4; ++k) {
    float4 v = sp[k];
    int cb = csub + k * 4;
    tile[cb + 0][r] = v.x;
    tile[cb + 1][r] = v.y;
    tile[cb + 2][r] = v.z;
    tile[cb + 3][r] = v.w;
  }
  __syncthreads();
  int cw = t >> 2;                 // output row (= source col)
  int rsub = (t & 3) << 4;
  #pragma unroll
  for (int h = 0; h < 2; ++h) {
    ush8 o;
    #pragma unroll
    for (int e = 0; e < 8; ++e) o[e] = f2h(tile[cw][rsub + h * 8 + e]);
    *(ush8*)(dst + (size_t)(c0 + cw) * 512 + r0 + rsub + h * 8) = o;
  }
}

// ---- out[row] = sum_k A_f16[row][k] * vec[k], K=512, one wave per row ----------
__global__ __launch_bounds__(256) void dotrows_h(const unsigned short* __restrict__ A,
                                                 const float* __restrict__ vec,
                                                 float* __restrict__ out) {
  int row = blockIdx.x * 4 + (threadIdx.x >> 6);
  int lane = threadIdx.x & 63;
  ush8 a = *(const ush8*)(A + (size_t)row * 512 + lane * 8);
  float s = 0.f;
  #pragma unroll
  for (int e = 0; e < 8; ++e) s += h2f(a[e]) * vec[lane * 8 + e];
  #pragma unroll
  for (int o = 32; o; o >>= 1) s += __shfl_down(s, o);
  if (lane == 0) out[row] = s;
}

// ---- b2[o] = out_b[o] + sum_c out_w_f32[o][c] * h_b[c] -------------------------
__global__ __launch_bounds__(256) void b2_k(const float* __restrict__ Wf,
                                            const float* __restrict__ hb,
                                            const float* __restrict__ ob,
                                            float* __restrict__ out) {
  int row = blockIdx.x * 4 + (threadIdx.x >> 6);
  int lane = threadIdx.x & 63;
  const float4* a = (const float4*)(Wf + (size_t)row * 512) + lane * 2;
  float4 x0 = a[0], x1 = a[1];
  const float4* hv = (const float4*)hb + lane * 2;
  float4 h0 = hv[0], h1 = hv[1];
  float s = x0.x * h0.x + x0.y * h0.y + x0.z * h0.z + x0.w * h0.w
          + x1.x * h1.x + x1.y * h1.y + x1.z * h1.z + x1.w * h1.w;
  #pragma unroll
  for (int o = 32; o; o >>= 1) s += __shfl_down(s, o);
  if (lane == 0) out[row] = ob[row] + s;
}

// ------ row softmax over 4096 f16 IN PLACE (row pitch 4096 f16 = 8KB) -----------
__global__ __launch_bounds__(256) void softmax_h(unsigned short* __restrict__ S) {
  unsigned short* row = S + (size_t)blockIdx.x * HW;
  int t = threadIdx.x;
  ush8 a0 = *(const ush8*)(row + t * 16);
  ush8 a1 = *(const ush8*)(row + t * 16 + 8);
  float v[16];
  #pragma unroll
  for (int e = 0; e < 8; ++e) { v[e] = h2f(a0[e]); v[8 + e] = h2f(a1[e]); }
  float mx = -3.0e38f;
  #pragma unroll
  for (int e = 0; e < 16; ++e) mx = fmaxf(mx, v[e]);
  #pragma unroll
  for (int o = 32; o; o >>= 1) mx = fmaxf(mx, __shfl_down(mx, o));
  __shared__ float red[8];
  int w = t >> 6;
  if ((t & 63) == 0) red[w] = mx;
  __syncthreads();
  mx = fmaxf(fmaxf(red[0], red[1]), fmaxf(red[2], red[3]));
  float sum = 0.f;
  #pragma unroll
  for (int e = 0; e < 16; ++e) { v[e] = __expf(v[e] - mx); sum += v[e]; }
  #pragma unroll
  for (int o = 32; o; o >>= 1) sum += __shfl_down(sum, o);
  if ((t & 63) == 0) red[4 + w] = sum;
  __syncthreads();
  float inv = 1.f / ((red[4] + red[5]) + (red[6] + red[7]));
  ush8 o0, o1;
  #pragma unroll
  for (int e = 0; e < 8; ++e) { o0[e] = f2h(v[e] * inv); o1[e] = f2h(v[8 + e] * inv); }
  *(ush8*)(row + t * 16) = o0;
  *(ush8*)(row + t * 16 + 8) = o1;
}

// ------- split-K reduce: dense partials P4[bg][sp][m][c] -> f16 O ---------------
__global__ __launch_bounds__(256) void reduce_k(const float* __restrict__ P4,
                                                unsigned short* __restrict__ op,
                                                long long PSo, int R, int pzs) {
  int e = blockIdx.x * 256 + threadIdx.x;   // float4 output index over [G][R][NC/4]
  int bg = e >> pzs;
  int rem = e - (bg << pzs);                 // = m*(NC/4) + c4
  const float4* base = (const float4*)P4 + ((size_t)bg * 4) * R * (NC / 4) + rem;
  float4 s = {0.f, 0.f, 0.f, 0.f};
  #pragma unroll
  for (int sp = 0; sp < 4; ++sp) {
    float4 v = base[(size_t)sp * R * (NC / 4)];
    s.x += v.x; s.y += v.y; s.z += v.z; s.w += v.w;
  }
  int m = rem >> 7, c4 = rem & 127;
  ush4 o;
  o[0] = f2h(s.x); o[1] = f2h(s.y); o[2] = f2h(s.z); o[3] = f2h(s.w);
  *(ush4*)(op + (size_t)bg * PSo + (size_t)m * NC + c4 * 4) = o;
}

// --------- NT GEMM (128x128, 2-phase LDS dbuf): small/skinny matrices -----------
__global__ __launch_bounds__(256, 2) void gemm_ntp(
    const unsigned short* __restrict__ A, long long sA, int lda,
    const unsigned short* __restrict__ Bm, long long sB, int ldb,
    void* __restrict__ Cp, long long sC, long long sCs, int ldc,
    int K, int out_f32, int ls,
    const float* __restrict__ bias_m, const float* __restrict__ bias_n,
    const float* __restrict__ add_src, long long sAdd,
    const unsigned short* __restrict__ B2, const float* __restrict__ bias_n2,
    int zsw) {
  __shared__ short lsA[2][128 * 64];
  __shared__ short lsB[2][128 * 64];
  const int t = threadIdx.x;
  const int lane = t & 63;
  const int w = t >> 6;
  const int wm = w >> 1, wn = w & 1;
  const long long bz = blockIdx.z;
  if ((int)bz >= zsw) { Bm = B2; bias_n = bias_n2; }
  const long long bg = bz >> ls;
  const int sp = (int)(bz - (bg << ls));
  const long long koff = (long long)sp * K;
  const unsigned short* Ab = A + bz * sA * (ls ? 0 : 1) + (ls ? bg * sA : 0) + koff
                           + (size_t)blockIdx.x * 128 * lda;
  const unsigned short* Bb = Bm + bg * sB + koff + (size_t)blockIdx.y * 128 * ldb;

  f32x4 zero = {0.f, 0.f, 0.f, 0.f};
  f32x4 acc[4][4];
  #pragma unroll
  for (int i = 0; i < 4; ++i)
    #pragma unroll
    for (int j = 0; j < 4; ++j) acc[i][j] = zero;

  const int nkt = K >> 6;

  auto STAGE = [&](int buf, int kt) {
    const int kbase = kt << 6;
    #pragma unroll
    for (int i = 0; i < 4; ++i) {
      int q = t + i * 256;               // chunk id 0..1023
      int r = q >> 3, xx = q & 7;
      int gk = kbase + ((xx ^ (r & 7)) << 3);
      __builtin_amdgcn_global_load_lds((as1_cvp)(const void*)(Ab + (size_t)r * lda + gk),
                                       (as3_vp)(void*)(&lsA[buf][q << 3]), 16, 0, 0);
      __builtin_amdgcn_global_load_lds((as1_cvp)(const void*)(Bb + (size_t)r * ldb + gk),
                                       (as3_vp)(void*)(&lsB[buf][q << 3]), 16, 0, 0);
    }
  };

  STAGE(0, 0);
  __syncthreads();
  int cur = 0;
  for (int kt = 0; kt < nkt; ++kt) {
    if (kt + 1 < nkt) STAGE(cur ^ 1, kt + 1);   // prefetch issued before compute
    #pragma unroll
    for (int ks = 0; ks < 2; ++ks) {
      f16x8 av[4], bv[4];
      const int xl = ks * 4 + (lane >> 4);
      const int rr = lane & 15;
      #pragma unroll
      for (int mb = 0; mb < 4; ++mb) {
        int row = wm * 64 + mb * 16 + rr;
        av[mb] = *(const f16x8*)&lsA[cur][(row << 6) + ((xl ^ (row & 7)) << 3)];
      }
      #pragma unroll
      for (int nb = 0; nb < 4; ++nb) {
        int row = wn * 64 + nb * 16 + rr;
        bv[nb] = *(const f16x8*)&lsB[cur][(row << 6) + ((xl ^ (row & 7)) << 3)];
      }
      __builtin_amdgcn_s_setprio(1);
      #pragma unroll
      for (int mb = 0; mb < 4; ++mb)
        #pragma unroll
        for (int nb = 0; nb < 4; ++nb)
          acc[mb][nb] = __builtin_amdgcn_mfma_f32_16x16x32_f16(av[mb], bv[nb], acc[mb][nb], 0, 0, 0);
      __builtin_amdgcn_s_setprio(0);
    }
    __syncthreads();
    cur ^= 1;
  }

  const int mb0 = blockIdx.x * 128 + wm * 64;
  const int nb0 = blockIdx.y * 128 + wn * 64;
  const int cn = lane & 15;
  const int rq = (lane >> 4) << 2;
  float* cf = (float*)Cp;
  unsigned short* ch = (unsigned short*)Cp;
  #pragma unroll
  for (int mb = 0; mb < 4; ++mb) {
    #pragma unroll
    for (int nb = 0; nb < 4; ++nb) {
      int n = nb0 + nb * 16 + cn;
      float bn = bias_n ? bias_n[n] : 0.f;
      #pragma unroll
      for (int r = 0; r < 4; ++r) {
        int m = mb0 + mb * 16 + rq + r;
        float vv = acc[mb][nb][r] + bn;
        if (bias_m) vv += bias_m[m];
        if (add_src) vv += add_src[bg * sAdd + (size_t)m * ldc + n];
        size_t off = (size_t)(bg * sC) + (size_t)sp * sCs + (size_t)m * ldc + n;
        if (out_f32) cf[off] = vv;
        else ch[off] = f2h(vv);
      }
    }
  }
}

// --------- NT GEMM-Q: 256x256 tile, BK=32, 4-slot LDS ring, counted vmcnt -------
// 512 thr = 8 waves (2Mx4N), per-wave 128x64 out. Iteration kt: stage tile kt+3
// into slot (kt+3)&3 (freed at iter kt-1, all waves past that barrier -> no
// race); compute tile kt (12 ds_read_b128 + 32 MFMA per wave; MFMAs consume all
// reads before the barrier); then s_waitcnt vmcnt(8) (= 2 tiles x 4 loads still
// in flight, never 0) + raw s_barrier. Per-wave FIFO vmcnt + barrier ==> tile
// kt+1 collectively landed. Loads consumed ~3 iters (~900cy) after issue.
// Requires nkt >= 4. Bank swizzle: chunk ^ ((row>>1)&3) -> 2-way only (free).
__global__ __launch_bounds__(512, 2) void gemm_ntq(
    const unsigned short* __restrict__ A, long long sA, int lda,
    const unsigned short* __restrict__ Bm, long long sB, int ldb,
    void* __restrict__ Cp, long long sC, long long sCs, int ldc,
    int K, int out_f32, int ls,
    const float* __restrict__ bias_n, long long sBn) {
  __shared__ short lsA[4][256 * 32];
  __shared__ short lsB[4][256 * 32];
  const int t = threadIdx.x;
  const int lane = t & 63;
  const int w = t >> 6;          // 0..7
  const int wm = w >> 2, wn = w & 3;
  const long long bz = blockIdx.z;
  const long long bg = bz >> ls;
  const int sp = (int)(bz - (bg << ls));
  const long long koff = (long long)sp * K;
  const unsigned short* Ab = A + bg * sA + koff + (size_t)blockIdx.x * 256 * lda;
  const unsigned short* Bb = Bm + bg * sB + koff + (size_t)blockIdx.y * 256 * ldb;

  f32x4 zero = {0.f, 0.f, 0.f, 0.f};
  f32x4 acc[8][4];
  #pragma unroll
  for (int i = 0; i < 8; ++i)
    #pragma unroll
    for (int j = 0; j < 4; ++j) acc[i][j] = zero;

  const int rr = lane & 15;
  const int xl = lane >> 4;
  const int nkt = K >> 5;          // BK = 32

  auto STAGE = [&](int kt) {       // 2 A-loads + 2 B-loads per thread (4 vmcnt)
    const int slot = kt & 3;
    const int kbase = kt << 5;
    #pragma unroll
    for (int i = 0; i < 2; ++i) {
      int q = t + i * 512;         // chunk-of-8 id, 0..1023 (256 rows x 4 chunks)
      int r = q >> 2, xx = q & 3;
      int gk = kbase + ((xx ^ ((r >> 1) & 3)) << 3);
      __builtin_amdgcn_global_load_lds((as1_cvp)(const void*)(Ab + (size_t)r * lda + gk),
                                       (as3_vp)(void*)(&lsA[slot][q << 3]), 16, 0, 0);
      __builtin_amdgcn_global_load_lds((as1_cvp)(const void*)(Bb + (size_t)r * ldb + gk),
                                       (as3_vp)(void*)(&lsB[slot][q << 3]), 16, 0, 0);
    }
  };

  auto COMPUTE = [&](int kt) {
    const int slot = kt & 3;
    f16x8 av[8], bv[4];
    #pragma unroll
    for (int mb = 0; mb < 8; ++mb) {
      int row = wm * 128 + mb * 16 + rr;
      av[mb] = *(const f16x8*)&lsA[slot][(row << 5) + ((xl ^ ((row >> 1) & 3)) << 3)];
    }
    #pragma unroll
    for (int nb = 0; nb < 4; ++nb) {
      int row = wn * 64 + nb * 16 + rr;
      bv[nb] = *(const f16x8*)&lsB[slot][(row << 5) + ((xl ^ ((row >> 1) & 3)) << 3)];
    }
    __builtin_amdgcn_s_setprio(1);
    #pragma unroll
    for (int mb = 0; mb < 8; ++mb)
      #pragma unroll
      for (int nb = 0; nb < 4; ++nb)
        acc[mb][nb] = __builtin_amdgcn_mfma_f32_16x16x32_f16(av[mb], bv[nb], acc[mb][nb], 0, 0, 0);
    __builtin_amdgcn_s_setprio(0);
  };

  // prologue: 3 tiles in flight; wait own tile-0 loads (12 out -> 8) + barrier
  STAGE(0); STAGE(1); STAGE(2);
  asm volatile("s_waitcnt vmcnt(8)" ::: "memory");
  __builtin_amdgcn_s_barrier();
  __builtin_amdgcn_sched_barrier(0);

  int kt = 0;
  for (; kt + 3 < nkt; ++kt) {
    STAGE(kt + 3);
    COMPUTE(kt);
    asm volatile("s_waitcnt vmcnt(8)" ::: "memory");
    __builtin_amdgcn_s_barrier();
    __builtin_amdgcn_sched_barrier(0);
  }
  // tail: nkt-3, nkt-2, nkt-1 (no more stages; drain 4 -> 0)
  COMPUTE(kt);
  asm volatile("s_waitcnt vmcnt(4)" ::: "memory");
  __builtin_amdgcn_s_barrier();
  __builtin_amdgcn_sched_barrier(0);
  ++kt;
  COMPUTE(kt);
  asm volatile("s_waitcnt vmcnt(0)" ::: "memory");
  __builtin_amdgcn_s_barrier();
  __builtin_amdgcn_sched_barrier(0);
  ++kt;
  COMPUTE(kt);

  const int mb0 = blockIdx.x * 256 + wm * 128;
  const int nb0 = blockIdx.y * 256 + wn * 64;
  const int cn = lane & 15;
  const int rq = (lane >> 4) << 2;
  float* cf = (float*)Cp;
  unsigned short* ch = (unsigned short*)Cp;
  #pragma unroll
  for (int mb = 0; mb < 8; ++mb) {
    #pragma unroll
    for (int nb = 0; nb < 4; ++nb) {
      int n = nb0 + nb * 16 + cn;
      float bn = bias_n ? bias_n[bg * sBn + n] : 0.f;
      #pragma unroll
      for (int r = 0; r < 4; ++r) {
        int m = mb0 + mb * 16 + rq + r;
        float vv = acc[mb][nb][r] + bn;
        size_t off = (size_t)(bg * sC) + (size_t)sp * sCs + (size_t)m * ldc + n;
        if (out_f32) cf[off] = vv;
        else ch[off] = f2h(vv);
      }
    }
  }
}

extern "C" void kernel_launch(void* const* d_in, const int* in_sizes, int n_in,
                              void* d_out, int out_size, void* d_ws, size_t ws_size,
                              hipStream_t stream) {
  const float* x = (const float*)d_in[0];
  const float* y = (const float*)d_in[1];
  const float* f_w = (const float*)d_in[2];
  const float* f_b = (const float*)d_in[3];
  const float* g_w = (const float*)d_in[4];
  const float* g_b = (const float*)d_in[5];  // dropped: row-constant shift, softmax-exact
  const float* h_w = (const float*)d_in[6];
  const float* h_b = (const float*)d_in[7];
  const float* out_w = (const float*)d_in[8];
  const float* out_b = (const float*)d_in[9];
  float* out = (float*)d_out;
  (void)g_b;

  char* ws = (char*)d_ws;
  size_t off = 0;
  auto alloc = [&](size_t bytes) -> char* {
    char* p = ws + off;
    off += (bytes + 255) & ~(size_t)255;
    return p;
  };
  const size_t TN = (size_t)NB * HW * NC;  // elems per [B][HW][C] buf
  const size_t WN = (size_t)512 * 512;
  float* stats = (float*)alloc(8192 * sizeof(float));
  unsigned short* fwT = (unsigned short*)alloc(WN * 2);
  unsigned short* gwT = (unsigned short*)alloc(WN * 2);
  unsigned short* hwT = (unsigned short*)alloc(WN * 2);
  unsigned short* owB = (unsigned short*)alloc(WN * 2);
  unsigned short* W1T = (unsigned short*)alloc(WN * 2);
  unsigned short* W2 = (unsigned short*)alloc(WN * 2);
  float* vv = (float*)alloc(512 * 4);
  float* b2 = (float*)alloc(512 * 4);
  float* wj = (float*)alloc((size_t)NB * HW * 4);
  unsigned short* xnT = (unsigned short*)alloc(TN * 2);
  unsigned short* ynT = (unsigned short*)alloc(TN * 2);
  unsigned short* yH = (unsigned short*)alloc(TN * 2);
  unsigned short* fB = (unsigned short*)alloc(TN * 2);    // F2
  unsigned short* oB = xnT;      // alias: xnT dead after F2-GEMM
  size_t remain = ws_size > off ? ws_size - off : 0;
  // per-batch attention footprint: S f16 (32MB) + P4 f32 (32MB) = 64MB
  const size_t SB = (size_t)HW * HW * 2 + (size_t)4 * HW * NC * 4;
  int G, R = HW;
  if (remain >= 4 * SB)      { G = 4; }
  else if (remain >= 2 * SB) { G = 2; }    // expected path
  else if (remain >= SB)     { G = 1; }
  else {
    G = 1;
    while (R > 128 && (size_t)R * (HW * 2 + 16 * NC) > remain) R >>= 1;
  }
  unsigned short* Sh = (unsigned short*)alloc((size_t)G * R * HW * 2);
  float* P4 = (float*)alloc((size_t)G * 4 * R * NC * 4);
  if (off > ws_size) return;  // scratch too small; cannot run

  const long long PS = (long long)HW * NC;  // per-batch stride (elements)
  const int BIG = 1 << 30;

  castw_k<<<dim3(8, 8, 4), dim3(256), 0, stream>>>(f_w, g_w, h_w, out_w,
                                                   fwT, gwT, hwT, owB);
  moments_k<<<dim3(4096), dim3(256), 0, stream>>>(x, y, stats);
  transnorm_k<<<dim3(64, 8, 8), dim3(256), 0, stream>>>(x, y, stats, xnT, ynT, yH);

  // v[c] = sum_o Gw[o][c] f_b[o] ; b2[o] = out_b[o] + sum_c OutW[o][c] h_b[c]
  dotrows_h<<<dim3(128), dim3(256), 0, stream>>>(gwT, f_b, vv);
  b2_k<<<dim3(128), dim3(256), 0, stream>>>(out_w, h_b, out_b, b2);
  // W1T[c2][c1] = sum_o Gw[o][c2] Fw[o][c1]   (= (Fw^T Gw)^T, F2's B-operand)
  gemm_ntp<<<dim3(4, 4, 1), dim3(256), 0, stream>>>(
      gwT, 0, 512, fwT, 0, 512, W1T, 0, 0, 512, 512, 0, 0,
      nullptr, nullptr, nullptr, 0, nullptr, nullptr, BIG);
  // W2[o][c'] = sum_c OutW[o][c] Hw[c][c']
  gemm_ntp<<<dim3(4, 4, 1), dim3(256), 0, stream>>>(
      owB, 0, 512, hwT, 0, 512, W2, 0, 0, 512, 512, 0, 0,
      nullptr, nullptr, nullptr, 0, nullptr, nullptr, BIG);
  // w[b][j] = Yn[b][j] . v
  dotrows_h<<<dim3(NB * HW / 4), dim3(256), 0, stream>>>(ynT, vv, wj);
  // F2[b][i][c'] = Xn . W1
  gemm_ntp<<<dim3(32, 4, NB), dim3(256), 0, stream>>>(
      xnT, PS, NC, W1T, 0, NC, fB, PS, 0, NC, NC, 0, 0,
      nullptr, nullptr, nullptr, 0, nullptr, nullptr, BIG);

  const int pzs = 31 - __builtin_clz((unsigned)(R * (NC / 4)));  // log2 f32x4 per bg
  for (int b0 = 0; b0 < NB; b0 += G) {
    for (int r0 = 0; r0 < HW; r0 += R) {
      if (R >= 256) {
        // E[bg][i][j] = F2[i][:] . Yn[j][:] + w[bg][j]  -> f16, pitch HW
        gemm_ntq<<<dim3(R / 256, HW / 256, G), dim3(512), 0, stream>>>(
            fB + ((size_t)b0 * HW + r0) * NC, PS, NC,
            ynT + (size_t)b0 * PS, PS, NC,
            Sh, (long long)R * HW, 0, HW, NC, 0, 0,
            wj + (size_t)b0 * HW, HW);
        softmax_h<<<dim3(G * R), dim3(256), 0, stream>>>(Sh);
        // Z partials: Z[i][c'] = P[i][:] . y[c'][:]  — split-K=4, dense P4 f32
        gemm_ntq<<<dim3(R / 256, NC / 256, G * 4), dim3(512), 0, stream>>>(
            Sh, (long long)R * HW, HW,
            yH + (size_t)b0 * NC * HW, (long long)NC * HW, HW,
            P4, (long long)4 * R * NC, (long long)R * NC, NC, HW / 4, 1, 2,
            nullptr, 0);
      } else {
        gemm_ntp<<<dim3(R / 128, 32, G), dim3(256), 0, stream>>>(
            fB + ((size_t)b0 * HW + r0) * NC, PS, NC,
            ynT + (size_t)b0 * PS, PS, NC,
            Sh, (long long)R * HW, 0, HW, NC, 0, 0,
            nullptr, wj + (size_t)b0 * HW, nullptr, 0, nullptr, nullptr, BIG);
        softmax_h<<<dim3(G * R), dim3(256), 0, stream>>>(Sh);
        gemm_ntp<<<dim3(R / 128, 4, G * 4), dim3(256), 0, stream>>>(
            Sh, (long long)R * HW, HW,
            yH + (size_t)b0 * NC * HW, (long long)NC * HW, HW,
            P4, (long long)4 * R * NC, (long long)R * NC, NC, HW / 4, 1, 2,
            nullptr, nullptr, nullptr, 0, nullptr, nullptr, BIG);
      }
      reduce_k<<<dim3(G * R / 2), dim3(256), 0, stream>>>(
          P4, oB + ((size_t)b0 * HW + r0) * NC, PS, R, pzs);
    }
  }
  // out[b][o][i] = W2 . Z^T + b2[o] + x   (f32 out)
  gemm_ntp<<<dim3(4, 32, NB), dim3(256), 0, stream>>>(
      W2, 0, NC, oB, PS, NC,
      out, (long long)NC * HW, 0, HW, NC, 1, 0,
      b2, nullptr, x, (long long)NC * HW, nullptr, nullptr, BIG);
}

// Round 12
// 380.843 us; speedup vs baseline: 1.1511x; 1.1511x over previous
//
#include <hip/hip_runtime.h>
#include <stdint.h>

#define HW 4096
#define NC 512
#define NB 4

typedef __attribute__((ext_vector_type(8))) _Float16 f16x8;
typedef __attribute__((ext_vector_type(4))) float f32x4;
typedef __attribute__((ext_vector_type(4))) unsigned short ush4;
typedef __attribute__((ext_vector_type(8))) unsigned short ush8;

typedef __attribute__((address_space(1))) const void* as1_cvp;
typedef __attribute__((address_space(3))) void* as3_vp;

__device__ __forceinline__ unsigned short f2h(float f) {
  union { _Float16 h; unsigned short u; } c;
  c.h = (_Float16)f;           // hardware v_cvt_f16_f32, RNE
  return c.u;
}
__device__ __forceinline__ float h2f(unsigned short u) {
  union { unsigned short u; _Float16 h; } c;
  c.u = u;
  return (float)c.h;
}

// ---------------- moments: per-(b,c) mean/rstd over 4096 spatial elems ----------
__global__ __launch_bounds__(256) void moments_k(const float* __restrict__ x,
                                                 const float* __restrict__ y,
                                                 float* __restrict__ stats) {
  int bid = blockIdx.x;          // 0..4095 : [tensor(2)][b*C+c (2048)]
  int tens = bid >> 11;
  int row = bid & 2047;
  const float* src = (tens ? y : x) + (size_t)row * HW;
  float s = 0.f, s2 = 0.f;
  for (int j = threadIdx.x; j < HW / 4; j += 256) {
    float4 v = ((const float4*)src)[j];
    s += (v.x + v.y) + (v.z + v.w);
    s2 += (v.x * v.x + v.y * v.y) + (v.z * v.z + v.w * v.w);
  }
  #pragma unroll
  for (int o = 32; o; o >>= 1) { s += __shfl_down(s, o); s2 += __shfl_down(s2, o); }
  __shared__ float rs[8];
  int w = threadIdx.x >> 6;
  if ((threadIdx.x & 63) == 0) { rs[w] = s; rs[4 + w] = s2; }
  __syncthreads();
  if (threadIdx.x == 0) {
    float S = (rs[0] + rs[1]) + (rs[2] + rs[3]);
    float S2 = (rs[4] + rs[5]) + (rs[6] + rs[7]);
    float mean = S * (1.f / HW);
    float var = S2 * (1.f / HW) - mean * mean;
    stats[tens * 4096 + row] = mean;
    stats[tens * 4096 + 2048 + row] = rsqrtf(var + 1e-5f);
  }
}

// ---- transpose f32 [c][i] -> f16 [i][c]; mode0: xnT; mode1: ynT + yH cast ------
__global__ __launch_bounds__(256) void transnorm_k(const float* __restrict__ x,
                                                   const float* __restrict__ y,
                                                   const float* __restrict__ stats,
                                                   unsigned short* __restrict__ xnT,
                                                   unsigned short* __restrict__ ynT,
                                                   unsigned short* __restrict__ yH) {
  __shared__ float tile[64][65];
  __shared__ float ms[64], rsd[64];
  int zi = blockIdx.z;            // [0,8): b = zi>>1, mode = zi&1
  int b = zi >> 1, mode = zi & 1;
  int i0 = blockIdx.x * 64, c0 = blockIdx.y * 64;
  const float* src = mode ? y : x;
  int t = threadIdx.x;
  int c = t >> 2;                 // 0..63
  int isub = (t & 3) << 4;        // 16 i's per thread
  if (t < 64) {
    int srow = (mode ? 4096 : 0) + b * NC + c0 + t;
    ms[t] = stats[srow];
    rsd[t] = stats[srow + 2048];
  }
  const float4* sp = (const float4*)(src + ((size_t)(b * NC + c0 + c)) * HW + i0 + isub);
  #pragma unroll
  for (int k = 0; k < 4; ++k) {
    float4 v = sp[k];
    int ib = isub + k * 4;
    tile[ib + 0][c] = v.x;
    tile[ib + 1][c] = v.y;
    tile[ib + 2][c] = v.z;
    tile[ib + 3][c] = v.w;
    if (mode) {   // straight f16 cast of raw y, [c][i] layout (PV B-operand)
      ush4 yo;
      yo[0] = f2h(v.x); yo[1] = f2h(v.y); yo[2] = f2h(v.z); yo[3] = f2h(v.w);
      *(ush4*)(yH + ((size_t)(b * NC + c0 + c)) * HW + i0 + isub + k * 4) = yo;
    }
  }
  __syncthreads();
  int i = t >> 2;
  int cc = (t & 3) << 4;
  size_t obase = ((size_t)b * HW + i0 + i) * NC + c0 + cc;
  unsigned short* dst = mode ? ynT : xnT;
  #pragma unroll
  for (int h = 0; h < 2; ++h) {
    ush8 o;
    #pragma unroll
    for (int e = 0; e < 8; ++e) {
      int ce = cc + h * 8 + e;
      o[e] = f2h((tile[i][ce] - ms[ce]) * rsd[ce]);
    }
    *(ush8*)(dst + obase + h * 8) = o;
  }
}

// ---- weights -> f16: z=0,1,2 transpose fw,gw,hw ; z=3 straight out_w -----------
__global__ __launch_bounds__(256) void castw_k(const float* __restrict__ fw,
                                               const float* __restrict__ gw,
                                               const float* __restrict__ hw_,
                                               const float* __restrict__ ow,
                                               unsigned short* __restrict__ fwT,
                                               unsigned short* __restrict__ gwT,
                                               unsigned short* __restrict__ hwT,
                                               unsigned short* __restrict__ owB) {
  __shared__ float tile[64][65];
  int which = blockIdx.z;
  const float* src = which == 0 ? fw : which == 1 ? gw : which == 2 ? hw_ : ow;
  unsigned short* dst = which == 0 ? fwT : which == 1 ? gwT : which == 2 ? hwT : owB;
  int r0 = blockIdx.x * 64, c0 = blockIdx.y * 64;
  int t = threadIdx.x;
  int r = t >> 2;
  int csub = (t & 3) << 4;
  const float4* sp = (const float4*)(src + (size_t)(r0 + r) * 512 + c0 + csub);
  if (which == 3) {   // straight cast
    #pragma unroll
    for (int k = 0; k < 4; ++k) {
      float4 v = sp[k];
      ush4 o;
      o[0] = f2h(v.x); o[1] = f2h(v.y); o[2] = f2h(v.z); o[3] = f2h(v.w);
      *(ush4*)(dst + (size_t)(r0 + r) * 512 + c0 + csub + k * 4) = o;
    }
    return;
  }
  #pragma unroll
  for (int k = 0; k < 4; ++k) {
    float4 v = sp[k];
    int cb = csub + k * 4;
    tile[cb + 0][r] = v.x;
    tile[cb + 1][r] = v.y;
    tile[cb + 2][r] = v.z;
    tile[cb + 3][r] = v.w;
  }
  __syncthreads();
  int cw = t >> 2;                 // output row (= source col)
  int rsub = (t & 3) << 4;
  #pragma unroll
  for (int h = 0; h < 2; ++h) {
    ush8 o;
    #pragma unroll
    for (int e = 0; e < 8; ++e) o[e] = f2h(tile[cw][rsub + h * 8 + e]);
    *(ush8*)(dst + (size_t)(c0 + cw) * 512 + r0 + rsub + h * 8) = o;
  }
}

// ---- replicate W2 [512][512] -> W2x2 [512][1024] (k mod 512) -------------------
__global__ __launch_bounds__(256) void repl_k(const unsigned short* __restrict__ W2,
                                              unsigned short* __restrict__ W2x2) {
  int idx = blockIdx.x * 256 + threadIdx.x;   // ush8 index over 512*1024/8
  int o = idx >> 7;
  int k = (idx & 127) * 8;
  ush8 v = *(const ush8*)(W2 + (size_t)o * 512 + (k & 511));
  *(ush8*)(W2x2 + (size_t)o * 1024 + k) = v;
}

// ---- out[row] = sum_k A_f16[row][k] * vec[k], K=512, one wave per row ----------
__global__ __launch_bounds__(256) void dotrows_h(const unsigned short* __restrict__ A,
                                                 const float* __restrict__ vec,
                                                 float* __restrict__ out) {
  int row = blockIdx.x * 4 + (threadIdx.x >> 6);
  int lane = threadIdx.x & 63;
  ush8 a = *(const ush8*)(A + (size_t)row * 512 + lane * 8);
  float s = 0.f;
  #pragma unroll
  for (int e = 0; e < 8; ++e) s += h2f(a[e]) * vec[lane * 8 + e];
  #pragma unroll
  for (int o = 32; o; o >>= 1) s += __shfl_down(s, o);
  if (lane == 0) out[row] = s;
}

// ---- b2[o] = out_b[o] + sum_c out_w_f32[o][c] * h_b[c] -------------------------
__global__ __launch_bounds__(256) void b2_k(const float* __restrict__ Wf,
                                            const float* __restrict__ hb,
                                            const float* __restrict__ ob,
                                            float* __restrict__ out) {
  int row = blockIdx.x * 4 + (threadIdx.x >> 6);
  int lane = threadIdx.x & 63;
  const float4* a = (const float4*)(Wf + (size_t)row * 512) + lane * 2;
  float4 x0 = a[0], x1 = a[1];
  const float4* hv = (const float4*)hb + lane * 2;
  float4 h0 = hv[0], h1 = hv[1];
  float s = x0.x * h0.x + x0.y * h0.y + x0.z * h0.z + x0.w * h0.w
          + x1.x * h1.x + x1.y * h1.y + x1.z * h1.z + x1.w * h1.w;
  #pragma unroll
  for (int o = 32; o; o >>= 1) s += __shfl_down(s, o);
  if (lane == 0) out[row] = ob[row] + s;
}

// ------ row softmax over 4096 f16 IN PLACE (row pitch 4096 f16 = 8KB) -----------
__global__ __launch_bounds__(256) void softmax_h(unsigned short* __restrict__ S) {
  unsigned short* row = S + (size_t)blockIdx.x * HW;
  int t = threadIdx.x;
  ush8 a0 = *(const ush8*)(row + t * 16);
  ush8 a1 = *(const ush8*)(row + t * 16 + 8);
  float v[16];
  #pragma unroll
  for (int e = 0; e < 8; ++e) { v[e] = h2f(a0[e]); v[8 + e] = h2f(a1[e]); }
  float mx = -3.0e38f;
  #pragma unroll
  for (int e = 0; e < 16; ++e) mx = fmaxf(mx, v[e]);
  #pragma unroll
  for (int o = 32; o; o >>= 1) mx = fmaxf(mx, __shfl_down(mx, o));
  __shared__ float red[8];
  int w = t >> 6;
  if ((t & 63) == 0) red[w] = mx;
  __syncthreads();
  mx = fmaxf(fmaxf(red[0], red[1]), fmaxf(red[2], red[3]));
  float sum = 0.f;
  #pragma unroll
  for (int e = 0; e < 16; ++e) { v[e] = __expf(v[e] - mx); sum += v[e]; }
  #pragma unroll
  for (int o = 32; o; o >>= 1) sum += __shfl_down(sum, o);
  if ((t & 63) == 0) red[4 + w] = sum;
  __syncthreads();
  float inv = 1.f / ((red[4] + red[5]) + (red[6] + red[7]));
  ush8 o0, o1;
  #pragma unroll
  for (int e = 0; e < 8; ++e) { o0[e] = f2h(v[e] * inv); o1[e] = f2h(v[8 + e] * inv); }
  *(ush8*)(row + t * 16) = o0;
  *(ush8*)(row + t * 16 + 8) = o1;
}

// --------- NT GEMM (128x128, 2-phase LDS dbuf): C[m][n] = sum_k A[m][k]*B[n][k] -
// Split-K: bz = bg*2^ls + sp; koff = sp*K; C off = bg*sC + sp*sCs + m*ldc + n.
// zsw: blocks with blockIdx.z >= zsw switch B operand/bias (fusion hook).
__global__ __launch_bounds__(256, 2) void gemm_ntp(
    const unsigned short* __restrict__ A, long long sA, int lda,
    const unsigned short* __restrict__ Bm, long long sB, int ldb,
    void* __restrict__ Cp, long long sC, long long sCs, int ldc,
    int K, int out_f32, int ls,
    const float* __restrict__ bias_m, const float* __restrict__ bias_n,
    const float* __restrict__ add_src, long long sAdd,
    const unsigned short* __restrict__ B2, const float* __restrict__ bias_n2,
    int zsw) {
  __shared__ short lsA[2][128 * 64];
  __shared__ short lsB[2][128 * 64];
  const int t = threadIdx.x;
  const int lane = t & 63;
  const int w = t >> 6;
  const int wm = w >> 1, wn = w & 1;
  const long long bz = blockIdx.z;
  if ((int)bz >= zsw) { Bm = B2; bias_n = bias_n2; }
  const long long bg = bz >> ls;
  const int sp = (int)(bz - (bg << ls));
  const long long koff = (long long)sp * K;
  const unsigned short* Ab = A + bz * sA * (ls ? 0 : 1) + (ls ? bg * sA : 0) + koff
                           + (size_t)blockIdx.x * 128 * lda;
  const unsigned short* Bb = Bm + bg * sB + koff + (size_t)blockIdx.y * 128 * ldb;

  f32x4 zero = {0.f, 0.f, 0.f, 0.f};
  f32x4 acc[4][4];
  #pragma unroll
  for (int i = 0; i < 4; ++i)
    #pragma unroll
    for (int j = 0; j < 4; ++j) acc[i][j] = zero;

  const int nkt = K >> 6;

  auto STAGE = [&](int buf, int kt) {
    const int kbase = kt << 6;
    #pragma unroll
    for (int i = 0; i < 4; ++i) {
      int q = t + i * 256;               // chunk id 0..1023
      int r = q >> 3, xx = q & 7;
      int gk = kbase + ((xx ^ (r & 7)) << 3);
      __builtin_amdgcn_global_load_lds((as1_cvp)(const void*)(Ab + (size_t)r * lda + gk),
                                       (as3_vp)(void*)(&lsA[buf][q << 3]), 16, 0, 0);
      __builtin_amdgcn_global_load_lds((as1_cvp)(const void*)(Bb + (size_t)r * ldb + gk),
                                       (as3_vp)(void*)(&lsB[buf][q << 3]), 16, 0, 0);
    }
  };

  STAGE(0, 0);
  __syncthreads();
  int cur = 0;
  for (int kt = 0; kt < nkt; ++kt) {
    if (kt + 1 < nkt) STAGE(cur ^ 1, kt + 1);   // prefetch issued before compute
    #pragma unroll
    for (int ks = 0; ks < 2; ++ks) {
      f16x8 av[4], bv[4];
      const int xl = ks * 4 + (lane >> 4);
      const int rr = lane & 15;
      #pragma unroll
      for (int mb = 0; mb < 4; ++mb) {
        int row = wm * 64 + mb * 16 + rr;
        av[mb] = *(const f16x8*)&lsA[cur][(row << 6) + ((xl ^ (row & 7)) << 3)];
      }
      #pragma unroll
      for (int nb = 0; nb < 4; ++nb) {
        int row = wn * 64 + nb * 16 + rr;
        bv[nb] = *(const f16x8*)&lsB[cur][(row << 6) + ((xl ^ (row & 7)) << 3)];
      }
      __builtin_amdgcn_s_setprio(1);
      #pragma unroll
      for (int mb = 0; mb < 4; ++mb)
        #pragma unroll
        for (int nb = 0; nb < 4; ++nb)
          acc[mb][nb] = __builtin_amdgcn_mfma_f32_16x16x32_f16(av[mb], bv[nb], acc[mb][nb], 0, 0, 0);
      __builtin_amdgcn_s_setprio(0);
    }
    __syncthreads();
    cur ^= 1;
  }

  const int mb0 = blockIdx.x * 128 + wm * 64;
  const int nb0 = blockIdx.y * 128 + wn * 64;
  const int cn = lane & 15;
  const int rq = (lane >> 4) << 2;
  float* cf = (float*)Cp;
  unsigned short* ch = (unsigned short*)Cp;
  #pragma unroll
  for (int mb = 0; mb < 4; ++mb) {
    #pragma unroll
    for (int nb = 0; nb < 4; ++nb) {
      int n = nb0 + nb * 16 + cn;
      float bn = bias_n ? bias_n[n] : 0.f;
      #pragma unroll
      for (int r = 0; r < 4; ++r) {
        int m = mb0 + mb * 16 + rq + r;
        float vv = acc[mb][nb][r] + bn;
        if (bias_m) vv += bias_m[m];
        if (add_src) vv += add_src[bg * sAdd + (size_t)m * ldc + n];
        size_t off = (size_t)(bg * sC) + (size_t)sp * sCs + (size_t)m * ldc + n;
        if (out_f32) cf[off] = vv;
        else ch[off] = f2h(vv);
      }
    }
  }
}

// --------- NT GEMM2 (256x256, 2-phase dbuf): energy only (per-z bias_n) ---------
__global__ __launch_bounds__(512, 2) void gemm_nt2(
    const unsigned short* __restrict__ A, long long sA, int lda,
    const unsigned short* __restrict__ Bm, long long sB, int ldb,
    void* __restrict__ Cp, long long sC, int ldc,
    int K, int out_f32,
    const float* __restrict__ bias_n, long long sBn) {
  __shared__ short lsA[2][256 * 64];
  __shared__ short lsB[2][256 * 64];
  const int t = threadIdx.x;
  const int lane = t & 63;
  const int w = t >> 6;          // 0..7
  const int wm = w >> 2, wn = w & 3;
  const long long bz = blockIdx.z;
  const unsigned short* Ab = A + bz * sA + (size_t)blockIdx.x * 256 * lda;
  const unsigned short* Bb = Bm + bz * sB + (size_t)blockIdx.y * 256 * ldb;

  f32x4 zero = {0.f, 0.f, 0.f, 0.f};
  f32x4 acc[8][4];
  #pragma unroll
  for (int i = 0; i < 8; ++i)
    #pragma unroll
    for (int j = 0; j < 4; ++j) acc[i][j] = zero;

  const int rr = lane & 15;
  const int xl = lane >> 4;
  const int nkt = K >> 6;

  auto STAGE = [&](int buf, int kt) {
    const int kbase = kt << 6;
    #pragma unroll
    for (int i = 0; i < 4; ++i) {
      int q = t + i * 512;               // chunk id 0..2047
      int r = q >> 3, xx = q & 7;
      int gk = kbase + ((xx ^ (r & 7)) << 3);
      __builtin_amdgcn_global_load_lds((as1_cvp)(const void*)(Ab + (size_t)r * lda + gk),
                                       (as3_vp)(void*)(&lsA[buf][q << 3]), 16, 0, 0);
      __builtin_amdgcn_global_load_lds((as1_cvp)(const void*)(Bb + (size_t)r * ldb + gk),
                                       (as3_vp)(void*)(&lsB[buf][q << 3]), 16, 0, 0);
    }
  };

  STAGE(0, 0);
  __syncthreads();
  int cur = 0;
  for (int kt = 0; kt < nkt; ++kt) {
    if (kt + 1 < nkt) STAGE(cur ^ 1, kt + 1);
    #pragma unroll
    for (int ks = 0; ks < 2; ++ks) {
      f16x8 av[8], bv[4];
      const int cb = ks * 4 + xl;
      #pragma unroll
      for (int mb = 0; mb < 8; ++mb) {
        int row = wm * 128 + mb * 16 + rr;
        av[mb] = *(const f16x8*)&lsA[cur][(row << 6) + ((cb ^ (row & 7)) << 3)];
      }
      #pragma unroll
      for (int nb = 0; nb < 4; ++nb) {
        int row = wn * 64 + nb * 16 + rr;
        bv[nb] = *(const f16x8*)&lsB[cur][(row << 6) + ((cb ^ (row & 7)) << 3)];
      }
      __builtin_amdgcn_s_setprio(1);
      #pragma unroll
      for (int mb = 0; mb < 8; ++mb)
        #pragma unroll
        for (int nb = 0; nb < 4; ++nb)
          acc[mb][nb] = __builtin_amdgcn_mfma_f32_16x16x32_f16(av[mb], bv[nb], acc[mb][nb], 0, 0, 0);
      __builtin_amdgcn_s_setprio(0);
    }
    __syncthreads();
    cur ^= 1;
  }

  const int mb0 = blockIdx.x * 256 + wm * 128;
  const int nb0 = blockIdx.y * 256 + wn * 64;
  const int cn = lane & 15;
  const int rq = (lane >> 4) << 2;
  float* cf = (float*)Cp;
  unsigned short* ch = (unsigned short*)Cp;
  #pragma unroll
  for (int mb = 0; mb < 8; ++mb) {
    #pragma unroll
    for (int nb = 0; nb < 4; ++nb) {
      int n = nb0 + nb * 16 + cn;
      float bn = bias_n ? bias_n[bz * sBn + n] : 0.f;
      #pragma unroll
      for (int r = 0; r < 4; ++r) {
        int m = mb0 + mb * 16 + rq + r;
        float vv = acc[mb][nb][r] + bn;
        size_t off = (size_t)(bz * sC) + (size_t)m * ldc + n;
        if (out_f32) cf[off] = vv;
        else ch[off] = f2h(vv);
      }
    }
  }
}

extern "C" void kernel_launch(void* const* d_in, const int* in_sizes, int n_in,
                              void* d_out, int out_size, void* d_ws, size_t ws_size,
                              hipStream_t stream) {
  const float* x = (const float*)d_in[0];
  const float* y = (const float*)d_in[1];
  const float* f_w = (const float*)d_in[2];
  const float* f_b = (const float*)d_in[3];
  const float* g_w = (const float*)d_in[4];
  const float* g_b = (const float*)d_in[5];  // dropped: row-constant shift, softmax-exact
  const float* h_w = (const float*)d_in[6];
  const float* h_b = (const float*)d_in[7];
  const float* out_w = (const float*)d_in[8];
  const float* out_b = (const float*)d_in[9];
  float* out = (float*)d_out;
  (void)g_b;

  char* ws = (char*)d_ws;
  size_t off = 0;
  auto alloc = [&](size_t bytes) -> char* {
    char* p = ws + off;
    off += (bytes + 255) & ~(size_t)255;
    return p;
  };
  const size_t TN = (size_t)NB * HW * NC;  // elems per [B][HW][C] buf
  const size_t WN = (size_t)512 * 512;
  float* stats = (float*)alloc(8192 * sizeof(float));
  unsigned short* fwT = (unsigned short*)alloc(WN * 2);
  unsigned short* gwT = (unsigned short*)alloc(WN * 2);
  unsigned short* hwT = (unsigned short*)alloc(WN * 2);
  unsigned short* owB = (unsigned short*)alloc(WN * 2);
  unsigned short* W1T = (unsigned short*)alloc(WN * 2);
  unsigned short* W2 = (unsigned short*)alloc(WN * 2);
  unsigned short* W2x2 = (unsigned short*)alloc((size_t)512 * 1024 * 2);
  float* vv = (float*)alloc(512 * 4);
  float* b2 = (float*)alloc(512 * 4);
  float* wj = (float*)alloc((size_t)NB * HW * 4);
  unsigned short* xnT = (unsigned short*)alloc(TN * 2);
  unsigned short* ynT = (unsigned short*)alloc(TN * 2);
  unsigned short* yH = (unsigned short*)alloc(TN * 2);
  unsigned short* fB = (unsigned short*)alloc(TN * 2);    // F2
  unsigned short* Zp = (unsigned short*)alloc((size_t)NB * HW * 1024 * 2);  // 32MB
  size_t remain = ws_size > off ? ws_size - off : 0;
  // per-batch attention footprint now: S f16 only (32MB)
  const size_t SB = (size_t)HW * HW * 2;
  int G, R = HW;
  if (remain >= 4 * SB)      { G = 4; }
  else if (remain >= 2 * SB) { G = 2; }    // expected path
  else if (remain >= SB)     { G = 1; }
  else {
    G = 1;
    while (R > 128 && (size_t)R * HW * 2 > remain) R >>= 1;
  }
  unsigned short* Sh = (unsigned short*)alloc((size_t)G * R * HW * 2);
  if (off > ws_size) return;  // scratch too small; cannot run

  const long long PS = (long long)HW * NC;  // per-batch stride (elements)
  const int BIG = 1 << 30;

  castw_k<<<dim3(8, 8, 4), dim3(256), 0, stream>>>(f_w, g_w, h_w, out_w,
                                                   fwT, gwT, hwT, owB);
  moments_k<<<dim3(4096), dim3(256), 0, stream>>>(x, y, stats);
  transnorm_k<<<dim3(64, 8, 8), dim3(256), 0, stream>>>(x, y, stats, xnT, ynT, yH);

  // v[c] = sum_o Gw[o][c] f_b[o] ; b2[o] = out_b[o] + sum_c OutW[o][c] h_b[c]
  dotrows_h<<<dim3(128), dim3(256), 0, stream>>>(gwT, f_b, vv);
  b2_k<<<dim3(128), dim3(256), 0, stream>>>(out_w, h_b, out_b, b2);
  // W1T[c2][c1] = sum_o Gw[o][c2] Fw[o][c1]   (= (Fw^T Gw)^T, F2's B-operand)
  gemm_ntp<<<dim3(4, 4, 1), dim3(256), 0, stream>>>(
      gwT, 0, 512, fwT, 0, 512, W1T, 0, 0, 512, 512, 0, 0,
      nullptr, nullptr, nullptr, 0, nullptr, nullptr, BIG);
  // W2[o][c'] = sum_c OutW[o][c] Hw[c][c']
  gemm_ntp<<<dim3(4, 4, 1), dim3(256), 0, stream>>>(
      owB, 0, 512, hwT, 0, 512, W2, 0, 0, 512, 512, 0, 0,
      nullptr, nullptr, nullptr, 0, nullptr, nullptr, BIG);
  repl_k<<<dim3(256), dim3(256), 0, stream>>>(W2, W2x2);
  // w[b][j] = Yn[b][j] . v
  dotrows_h<<<dim3(NB * HW / 4), dim3(256), 0, stream>>>(ynT, vv, wj);
  // F2[b][i][c'] = Xn . W1
  gemm_ntp<<<dim3(32, 4, NB), dim3(256), 0, stream>>>(
      xnT, PS, NC, W1T, 0, NC, fB, PS, 0, NC, NC, 0, 0,
      nullptr, nullptr, nullptr, 0, nullptr, nullptr, BIG);

  for (int b0 = 0; b0 < NB; b0 += G) {
    for (int r0 = 0; r0 < HW; r0 += R) {
      if (R >= 256) {
        // E[bg][i][j] = F2[i][:] . Yn[j][:] + w[bg][j]  -> f16, pitch HW
        gemm_nt2<<<dim3(R / 256, HW / 256, G), dim3(512), 0, stream>>>(
            fB + ((size_t)b0 * HW + r0) * NC, PS, NC,
            ynT + (size_t)b0 * PS, PS, NC,
            Sh, (long long)R * HW, HW, NC, 0,
            wj + (size_t)b0 * HW, HW);
      } else {
        gemm_ntp<<<dim3(R / 128, 32, G), dim3(256), 0, stream>>>(
            fB + ((size_t)b0 * HW + r0) * NC, PS, NC,
            ynT + (size_t)b0 * PS, PS, NC,
            Sh, (long long)R * HW, 0, HW, NC, 0, 0,
            nullptr, wj + (size_t)b0 * HW, nullptr, 0, nullptr, nullptr, BIG);
      }
      // row softmax in place (f16)
      softmax_h<<<dim3(G * R), dim3(256), 0, stream>>>(Sh);
      // Zp[i][sp*512+c'] = P[i][sp-half] . y[c'][sp-half]  (f16, K-interleaved)
      gemm_ntp<<<dim3(R / 128, 4, G * 2), dim3(256), 0, stream>>>(
          Sh, (long long)R * HW, HW,
          yH + (size_t)b0 * NC * HW, (long long)NC * HW, HW,
          Zp + ((size_t)b0 * HW + r0) * 1024, (long long)R * 1024, 512, 1024,
          HW / 2, 0, 1,
          nullptr, nullptr, nullptr, 0, nullptr, nullptr, BIG);
    }
  }
  // out[b][o][i] = W2x2 . Zp^T + b2[o] + x   (f32 out; K=1024 folds the 2 splits)
  gemm_ntp<<<dim3(4, 32, NB), dim3(256), 0, stream>>>(
      W2x2, 0, 1024, Zp, (long long)HW * 1024, 1024,
      out, (long long)NC * HW, 0, HW, 1024, 1, 0,
      b2, nullptr, x, (long long)NC * HW, nullptr, nullptr, BIG);
}